// Round 1
// baseline (281.990 us; speedup 1.0000x reference)
//
#include <hip/hip_runtime.h>
#include <cstdint>
#include <cstddef>

// ---------------------------------------------------------------------------
// Attention_84155589198714: qkv = ctx @ W + b; causal softmax(q k^T / sqrt(N)); @ v
// B=4, N=2048, D=1024. All GEMMs in bf16 MFMA (16x16x32), fp32 accumulate.
// Softmax trick: scores are bounded (|s| < ~8), so no max-subtraction needed:
// P_unnorm = exp(s), row sums l via atomics, divide in PV epilogue.
// ---------------------------------------------------------------------------

typedef __attribute__((ext_vector_type(8))) __bf16 bf16x8;
typedef __attribute__((ext_vector_type(4))) float f32x4;

__device__ inline unsigned short f2bf(float f) {
  unsigned u = __float_as_uint(f);
  u = (u + 0x7FFFu + ((u >> 16) & 1u)) >> 16;  // RNE
  return (unsigned short)u;
}

// async global->LDS, 16 B per lane. LDS dest = wave-uniform base + lane*16.
__device__ inline void gld16(const void* g, void* l) {
  __builtin_amdgcn_global_load_lds(
      (const __attribute__((address_space(1))) unsigned int*)g,
      (__attribute__((address_space(3))) unsigned int*)l, 16, 0, 0);
}

// ---------------------------------------------------------------------------
// Shared 128x128-tile bf16 GEMM mainloop (m97 structure).
// A: [.. x K]-major rows (row stride strideA, bf16), rows tile = 128
// Bt: [.. x K]-major rows (row stride strideB, bf16), rows tile = 128 (these are C columns)
// C[m][n] = sum_k A[m][k] * Bt[n][k].  kIters iterations of BK=64.
// 256 threads = 4 waves in 2x2; each wave computes 64x64 via 4x4 frags of 16x16.
// ---------------------------------------------------------------------------
__device__ inline void mma_mainloop(const unsigned short* Abase, long strideA,
                                    const unsigned short* Bbase, long strideB,
                                    int kIters, f32x4 acc[4][4]) {
  __shared__ unsigned short As[128 * 64];
  __shared__ unsigned short Bs[128 * 64];
  const int tid = threadIdx.x;
  const int lane = tid & 63;
  const int wave = tid >> 6;
  const int ry = (wave >> 1) * 64;
  const int rx = (wave & 1) * 64;
  const int lrow = lane >> 3;        // 0..7 (row within 8-row chunk)
  const int lcol = (lane & 7) * 8;   // bf16 offset within 64-elem row

#pragma unroll
  for (int mi = 0; mi < 4; mi++)
#pragma unroll
    for (int nj = 0; nj < 4; nj++) acc[mi][nj] = (f32x4)(0.f);

  for (int kt = 0; kt < kIters; kt++) {
    const int k0 = kt * 64;
    __syncthreads();  // previous compute done before overwriting LDS
#pragma unroll
    for (int c = 0; c < 4; c++) {
      const int q = wave * 4 + c;     // chunk 0..15, wave-uniform
      const int row = q * 8 + lrow;   // tile row 0..127
      gld16(Abase + (size_t)row * strideA + k0 + lcol, &As[q * 512]);
      gld16(Bbase + (size_t)row * strideB + k0 + lcol, &Bs[q * 512]);
    }
    __syncthreads();  // compiler inserts vmcnt(0) drain here
#pragma unroll
    for (int kk = 0; kk < 64; kk += 32) {
      const int koff = kk + (lane >> 4) * 8;
      bf16x8 a[4], b[4];
#pragma unroll
      for (int mi = 0; mi < 4; mi++)
        a[mi] = *(const bf16x8*)&As[(ry + mi * 16 + (lane & 15)) * 64 + koff];
#pragma unroll
      for (int nj = 0; nj < 4; nj++)
        b[nj] = *(const bf16x8*)&Bs[(rx + nj * 16 + (lane & 15)) * 64 + koff];
#pragma unroll
      for (int mi = 0; mi < 4; mi++)
#pragma unroll
        for (int nj = 0; nj < 4; nj++)
          acc[mi][nj] = __builtin_amdgcn_mfma_f32_16x16x32_bf16(a[mi], b[nj], acc[mi][nj], 0, 0, 0);
    }
  }
}

// --------------------------- prep kernels ----------------------------------

// fp32 -> bf16, 4 elems/thread
__global__ void k_convert(const float* __restrict__ x, unsigned short* __restrict__ y, int n4) {
  int i = blockIdx.x * blockDim.x + threadIdx.x;
  if (i >= n4) return;
  float4 v = ((const float4*)x)[i];
  ushort4 o;
  o.x = f2bf(v.x); o.y = f2bf(v.y); o.z = f2bf(v.z); o.w = f2bf(v.w);
  ((ushort4*)y)[i] = o;
}

// W [1024][3072] fp32 -> Wt [3072][1024] bf16
__global__ void k_transpose_w(const float* __restrict__ W, unsigned short* __restrict__ Wt) {
  __shared__ unsigned short sm[64 * 65];
  const int n0 = blockIdx.x * 64;  // over 3072
  const int k0 = blockIdx.y * 64;  // over 1024
  for (int i = threadIdx.x; i < 4096; i += 256) {
    int r = i >> 6, c = i & 63;  // r = k_local, c = n_local (coalesced in c)
    sm[c * 65 + r] = f2bf(W[(size_t)(k0 + r) * 3072 + n0 + c]);
  }
  __syncthreads();
  for (int i = threadIdx.x; i < 4096; i += 256) {
    int r = i >> 6, c = i & 63;  // r = n_local, c = k_local
    Wt[(size_t)(n0 + r) * 1024 + k0 + c] = sm[r * 65 + c];
  }
}

// v slice of qkv [b][n][2048+d] -> vT [b][d][n] bf16
__global__ void k_transpose_v(const unsigned short* __restrict__ qkv, unsigned short* __restrict__ vT) {
  __shared__ unsigned short sm[64 * 65];
  const int b = blockIdx.z;
  const int d0 = blockIdx.x * 64;  // over 1024
  const int n0 = blockIdx.y * 64;  // over 2048
  const unsigned short* src = qkv + ((size_t)b * 2048) * 3072 + 2048;
  for (int i = threadIdx.x; i < 4096; i += 256) {
    int r = i >> 6, c = i & 63;  // r = n_local, c = d_local
    sm[c * 65 + r] = src[(size_t)(n0 + r) * 3072 + d0 + c];
  }
  __syncthreads();
  unsigned short* dst = vT + ((size_t)b * 1024) * 2048;
  for (int i = threadIdx.x; i < 4096; i += 256) {
    int r = i >> 6, c = i & 63;  // r = d_local, c = n_local
    dst[(size_t)(d0 + r) * 2048 + n0 + c] = sm[r * 65 + c];
  }
}

// --------------------------- GEMM kernels ----------------------------------

// qkv[m][n] = ctx_bf16[m][k] @ Wt[n][k] + bias[n], m in 8192, n in 3072, k=1024
__global__ __launch_bounds__(256) void k_gemm_qkv(const unsigned short* __restrict__ A,
                                                  const unsigned short* __restrict__ Bt,
                                                  const float* __restrict__ bias,
                                                  unsigned short* __restrict__ C) {
  f32x4 acc[4][4];
  const int tN0 = blockIdx.x * 128;
  const int tM0 = blockIdx.y * 128;
  mma_mainloop(A + (size_t)tM0 * 1024, 1024, Bt + (size_t)tN0 * 1024, 1024, 16, acc);
  const int lane = threadIdx.x & 63, wave = threadIdx.x >> 6;
  const int ry = (wave >> 1) * 64, rx = (wave & 1) * 64;
  const int col0 = lane & 15, rq = lane >> 4;
#pragma unroll
  for (int mi = 0; mi < 4; mi++)
#pragma unroll
    for (int nj = 0; nj < 4; nj++) {
      const int n = tN0 + rx + nj * 16 + col0;
      const float bv = bias[n];
#pragma unroll
      for (int r = 0; r < 4; r++) {
        const int m = tM0 + ry + mi * 16 + rq * 4 + r;
        C[(size_t)m * 3072 + n] = f2bf(acc[mi][nj][r] + bv);
      }
    }
}

// P_unnorm tile + row-sum atomics. grid (kb, qb, b), skip kb > qb.
__global__ __launch_bounds__(256) void k_scores(const unsigned short* __restrict__ qkv,
                                                unsigned short* __restrict__ P,
                                                float* __restrict__ l, float scale) {
  const int kb = blockIdx.x, qb = blockIdx.y, b = blockIdx.z;
  if (kb > qb) return;
  f32x4 acc[4][4];
  const unsigned short* A = qkv + ((size_t)(b * 2048 + qb * 128)) * 3072;         // q rows
  const unsigned short* B = qkv + ((size_t)(b * 2048 + kb * 128)) * 3072 + 1024;  // k rows
  mma_mainloop(A, 3072, B, 3072, 16, acc);
  const int lane = threadIdx.x & 63, wave = threadIdx.x >> 6;
  const int ry = (wave >> 1) * 64, rx = (wave & 1) * 64;
  const int col0 = lane & 15, rq = lane >> 4;
  unsigned short* Pb = P + ((size_t)(b * 2048 + qb * 128)) * 2048 + (size_t)kb * 128;
  float* lb = l + b * 2048 + qb * 128;
#pragma unroll
  for (int mi = 0; mi < 4; mi++) {
#pragma unroll
    for (int r = 0; r < 4; r++) {
      const int m_local = ry + mi * 16 + rq * 4 + r;
      const int qi = qb * 128 + m_local;
      float rowpart = 0.f;
#pragma unroll
      for (int nj = 0; nj < 4; nj++) {
        const int n_local = rx + nj * 16 + col0;
        const int kj = kb * 128 + n_local;
        float p = 0.f;
        if (kj <= qi) p = __expf(acc[mi][nj][r] * scale);  // bounded, no max needed
        rowpart += p;
        Pb[(size_t)m_local * 2048 + n_local] = f2bf(p);
      }
      // sum over the 16 lanes (same row, different cols)
      for (int off = 1; off < 16; off <<= 1) rowpart += __shfl_xor(rowpart, off, 64);
      if (col0 == 0) atomicAdd(&lb[m_local], rowpart);
    }
  }
}

// out[m][d] = (P[m][:] @ vT[d][:]) / l[m].  grid (db, qb, b); causal k-range.
__global__ __launch_bounds__(256) void k_pv(const unsigned short* __restrict__ P,
                                            const unsigned short* __restrict__ vT,
                                            const float* __restrict__ l,
                                            float* __restrict__ out) {
  const int db = blockIdx.x, qb = blockIdx.y, b = blockIdx.z;
  f32x4 acc[4][4];
  const unsigned short* A = P + ((size_t)(b * 2048 + qb * 128)) * 2048;
  const unsigned short* B = vT + ((size_t)(b * 1024 + db * 128)) * 2048;
  mma_mainloop(A, 2048, B, 2048, (qb + 1) * 2, acc);  // keys <= (qb+1)*128
  const int lane = threadIdx.x & 63, wave = threadIdx.x >> 6;
  const int ry = (wave >> 1) * 64, rx = (wave & 1) * 64;
  const int col0 = lane & 15, rq = lane >> 4;
  const float* lb = l + b * 2048 + qb * 128;
  float* ob = out + ((size_t)(b * 2048 + qb * 128)) * 1024 + db * 128;
#pragma unroll
  for (int mi = 0; mi < 4; mi++)
#pragma unroll
    for (int r = 0; r < 4; r++) {
      const int m_local = ry + mi * 16 + rq * 4 + r;
      const float inv = 1.0f / lb[m_local];
#pragma unroll
      for (int nj = 0; nj < 4; nj++) {
        const int n_local = rx + nj * 16 + col0;
        ob[(size_t)m_local * 1024 + n_local] = acc[mi][nj][r] * inv;
      }
    }
}

// ---------------------------------------------------------------------------

extern "C" void kernel_launch(void* const* d_in, const int* in_sizes, int n_in,
                              void* d_out, int out_size, void* d_ws, size_t ws_size,
                              hipStream_t stream) {
  const float* ctx  = (const float*)d_in[0];  // [4,2048,1024]
  const float* W    = (const float*)d_in[1];  // [1024,3072]
  const float* bias = (const float*)d_in[2];  // [3072]
  float* out = (float*)d_out;

  char* ws = (char*)d_ws;
  // workspace layout (bytes): total ~124 MB
  unsigned short* Actx = (unsigned short*)(ws + 0);          // 16,777,216
  unsigned short* Wt   = (unsigned short*)(ws + 16777216);   //  6,291,456
  unsigned short* qkv  = (unsigned short*)(ws + 23068672);   // 50,331,648
  unsigned short* vT   = (unsigned short*)(ws + 73400320);   // 16,777,216
  unsigned short* P    = (unsigned short*)(ws + 90177536);   // 33,554,432
  float*          lsum = (float*)(ws + 123731968);           //     32,768

  hipMemsetAsync(lsum, 0, 4 * 2048 * sizeof(float), stream);
  k_convert<<<8192, 256, 0, stream>>>(ctx, Actx, (8192 * 1024) / 4);
  k_transpose_w<<<dim3(48, 16), 256, 0, stream>>>(W, Wt);
  k_gemm_qkv<<<dim3(24, 64), 256, 0, stream>>>(Actx, Wt, bias, qkv);
  k_transpose_v<<<dim3(16, 32, 4), 256, 0, stream>>>(qkv, vT);
  k_scores<<<dim3(16, 16, 4), 256, 0, stream>>>(qkv, P, lsum, 0.022097086912079608f);
  k_pv<<<dim3(8, 16, 4), 256, 0, stream>>>(P, vT, lsum, out);
}

// Round 2
// 262.255 us; speedup vs baseline: 1.0752x; 1.0752x over previous
//
#include <hip/hip_runtime.h>
#include <cstdint>
#include <cstddef>

// ---------------------------------------------------------------------------
// Attention_84155589198714: qkv = ctx @ W + b; causal softmax(q k^T / sqrt(N)); @ v
// B=4, N=2048, D=1024. All GEMMs in bf16 MFMA (16x16x32), fp32 accumulate.
// Softmax trick: scores are bounded (|s| < ~8), so no max-subtraction needed:
// P_unnorm = exp(s), row sums l via atomics, divide in PV epilogue.
//
// R2: XOR bank-conflict swizzle on the LDS tile. Fragment reads previously hit
// a 16-way conflict (row stride 128 B == 32 banks). Chunk c of row r is now
// stored at position c ^ (r&7); global_load_lds source lanes permute within the
// same 128 B segment (coalescing preserved), reads fan across all 32 banks.
// ---------------------------------------------------------------------------

typedef __attribute__((ext_vector_type(8))) __bf16 bf16x8;
typedef __attribute__((ext_vector_type(4))) float f32x4;

__device__ inline unsigned short f2bf(float f) {
  unsigned u = __float_as_uint(f);
  u = (u + 0x7FFFu + ((u >> 16) & 1u)) >> 16;  // RNE
  return (unsigned short)u;
}

// async global->LDS, 16 B per lane. LDS dest = wave-uniform base + lane*16.
__device__ inline void gld16(const void* g, void* l) {
  __builtin_amdgcn_global_load_lds(
      (const __attribute__((address_space(1))) unsigned int*)g,
      (__attribute__((address_space(3))) unsigned int*)l, 16, 0, 0);
}

// ---------------------------------------------------------------------------
// Shared 128x128-tile bf16 GEMM mainloop (m97 structure + XOR swizzle).
// C[m][n] = sum_k A[m][k] * Bt[n][k].  kIters iterations of BK=64.
// 256 threads = 4 waves in 2x2; each wave computes 64x64 via 4x4 frags of 16x16.
// LDS layout: row r (0..127) occupies 64 elems; 8-elem chunk c of row r lives
// at element offset r*64 + ((c ^ (r&7))*8).
// ---------------------------------------------------------------------------
__device__ inline void mma_mainloop(const unsigned short* Abase, long strideA,
                                    const unsigned short* Bbase, long strideB,
                                    int kIters, f32x4 acc[4][4]) {
  __shared__ unsigned short As[128 * 64];
  __shared__ unsigned short Bs[128 * 64];
  const int tid = threadIdx.x;
  const int lane = tid & 63;
  const int wave = tid >> 6;
  const int ry = (wave >> 1) * 64;
  const int rx = (wave & 1) * 64;
  const int lrow = lane >> 3;                 // 0..7 (row within 8-row chunk)
  const int lchunk = (lane & 7) ^ lrow;       // swizzled source column-chunk
  const int lcol = lchunk * 8;                // bf16 offset within 64-elem row

#pragma unroll
  for (int mi = 0; mi < 4; mi++)
#pragma unroll
    for (int nj = 0; nj < 4; nj++) acc[mi][nj] = (f32x4)(0.f);

  for (int kt = 0; kt < kIters; kt++) {
    const int k0 = kt * 64;
    __syncthreads();  // previous compute done before overwriting LDS
#pragma unroll
    for (int c = 0; c < 4; c++) {
      const int q = wave * 4 + c;     // chunk 0..15, wave-uniform
      const int row = q * 8 + lrow;   // tile row 0..127
      gld16(Abase + (size_t)row * strideA + k0 + lcol, &As[q * 512]);
      gld16(Bbase + (size_t)row * strideB + k0 + lcol, &Bs[q * 512]);
    }
    __syncthreads();  // compiler inserts vmcnt(0) drain here
#pragma unroll
    for (int kk = 0; kk < 64; kk += 32) {
      const int cbase = (kk >> 3) + (lane >> 4);          // chunk 0..7
      const int csw = ((cbase ^ (lane & 7)) << 3);        // swizzled elem offset
      bf16x8 a[4], b[4];
#pragma unroll
      for (int mi = 0; mi < 4; mi++)
        a[mi] = *(const bf16x8*)&As[(ry + mi * 16 + (lane & 15)) * 64 + csw];
#pragma unroll
      for (int nj = 0; nj < 4; nj++)
        b[nj] = *(const bf16x8*)&Bs[(rx + nj * 16 + (lane & 15)) * 64 + csw];
#pragma unroll
      for (int mi = 0; mi < 4; mi++)
#pragma unroll
        for (int nj = 0; nj < 4; nj++)
          acc[mi][nj] = __builtin_amdgcn_mfma_f32_16x16x32_bf16(a[mi], b[nj], acc[mi][nj], 0, 0, 0);
    }
  }
}

// --------------------------- prep kernels ----------------------------------

// fp32 -> bf16, 4 elems/thread
__global__ void k_convert(const float* __restrict__ x, unsigned short* __restrict__ y, int n4) {
  int i = blockIdx.x * blockDim.x + threadIdx.x;
  if (i >= n4) return;
  float4 v = ((const float4*)x)[i];
  ushort4 o;
  o.x = f2bf(v.x); o.y = f2bf(v.y); o.z = f2bf(v.z); o.w = f2bf(v.w);
  ((ushort4*)y)[i] = o;
}

// W [1024][3072] fp32 -> Wt [3072][1024] bf16
__global__ void k_transpose_w(const float* __restrict__ W, unsigned short* __restrict__ Wt) {
  __shared__ unsigned short sm[64 * 65];
  const int n0 = blockIdx.x * 64;  // over 3072
  const int k0 = blockIdx.y * 64;  // over 1024
  for (int i = threadIdx.x; i < 4096; i += 256) {
    int r = i >> 6, c = i & 63;  // r = k_local, c = n_local (coalesced in c)
    sm[c * 65 + r] = f2bf(W[(size_t)(k0 + r) * 3072 + n0 + c]);
  }
  __syncthreads();
  for (int i = threadIdx.x; i < 4096; i += 256) {
    int r = i >> 6, c = i & 63;  // r = n_local, c = k_local
    Wt[(size_t)(n0 + r) * 1024 + k0 + c] = sm[r * 65 + c];
  }
}

// v slice of qkv [b][n][2048+d] -> vT [b][d][n] bf16
__global__ void k_transpose_v(const unsigned short* __restrict__ qkv, unsigned short* __restrict__ vT) {
  __shared__ unsigned short sm[64 * 65];
  const int b = blockIdx.z;
  const int d0 = blockIdx.x * 64;  // over 1024
  const int n0 = blockIdx.y * 64;  // over 2048
  const unsigned short* src = qkv + ((size_t)b * 2048) * 3072 + 2048;
  for (int i = threadIdx.x; i < 4096; i += 256) {
    int r = i >> 6, c = i & 63;  // r = n_local, c = d_local
    sm[c * 65 + r] = src[(size_t)(n0 + r) * 3072 + d0 + c];
  }
  __syncthreads();
  unsigned short* dst = vT + ((size_t)b * 1024) * 2048;
  for (int i = threadIdx.x; i < 4096; i += 256) {
    int r = i >> 6, c = i & 63;  // r = d_local, c = n_local
    dst[(size_t)(d0 + r) * 2048 + n0 + c] = sm[r * 65 + c];
  }
}

// --------------------------- GEMM kernels ----------------------------------

// qkv[m][n] = ctx_bf16[m][k] @ Wt[n][k] + bias[n], m in 8192, n in 3072, k=1024
__global__ __launch_bounds__(256) void k_gemm_qkv(const unsigned short* __restrict__ A,
                                                  const unsigned short* __restrict__ Bt,
                                                  const float* __restrict__ bias,
                                                  unsigned short* __restrict__ C) {
  f32x4 acc[4][4];
  const int tN0 = blockIdx.x * 128;
  const int tM0 = blockIdx.y * 128;
  mma_mainloop(A + (size_t)tM0 * 1024, 1024, Bt + (size_t)tN0 * 1024, 1024, 16, acc);
  const int lane = threadIdx.x & 63, wave = threadIdx.x >> 6;
  const int ry = (wave >> 1) * 64, rx = (wave & 1) * 64;
  const int col0 = lane & 15, rq = lane >> 4;
#pragma unroll
  for (int mi = 0; mi < 4; mi++)
#pragma unroll
    for (int nj = 0; nj < 4; nj++) {
      const int n = tN0 + rx + nj * 16 + col0;
      const float bv = bias[n];
#pragma unroll
      for (int r = 0; r < 4; r++) {
        const int m = tM0 + ry + mi * 16 + rq * 4 + r;
        C[(size_t)m * 3072 + n] = f2bf(acc[mi][nj][r] + bv);
      }
    }
}

// P_unnorm tile + row-sum atomics. 1-D triangular grid over (qb,kb), z = batch.
__global__ __launch_bounds__(256) void k_scores(const unsigned short* __restrict__ qkv,
                                                unsigned short* __restrict__ P,
                                                float* __restrict__ l, float scale) {
  const int t = blockIdx.x, b = blockIdx.z;
  int qb = (int)((sqrtf(8.0f * (float)t + 1.0f) - 1.0f) * 0.5f);
  while (qb * (qb + 1) / 2 > t) qb--;            // guard fp rounding
  while ((qb + 1) * (qb + 2) / 2 <= t) qb++;
  const int kb = t - qb * (qb + 1) / 2;
  f32x4 acc[4][4];
  const unsigned short* A = qkv + ((size_t)(b * 2048 + qb * 128)) * 3072;         // q rows
  const unsigned short* B = qkv + ((size_t)(b * 2048 + kb * 128)) * 3072 + 1024;  // k rows
  mma_mainloop(A, 3072, B, 3072, 16, acc);
  const int lane = threadIdx.x & 63, wave = threadIdx.x >> 6;
  const int ry = (wave >> 1) * 64, rx = (wave & 1) * 64;
  const int col0 = lane & 15, rq = lane >> 4;
  unsigned short* Pb = P + ((size_t)(b * 2048 + qb * 128)) * 2048 + (size_t)kb * 128;
  float* lb = l + b * 2048 + qb * 128;
#pragma unroll
  for (int mi = 0; mi < 4; mi++) {
#pragma unroll
    for (int r = 0; r < 4; r++) {
      const int m_local = ry + mi * 16 + rq * 4 + r;
      const int qi = qb * 128 + m_local;
      float rowpart = 0.f;
#pragma unroll
      for (int nj = 0; nj < 4; nj++) {
        const int n_local = rx + nj * 16 + col0;
        const int kj = kb * 128 + n_local;
        float p = 0.f;
        if (kj <= qi) p = __expf(acc[mi][nj][r] * scale);  // bounded, no max needed
        rowpart += p;
        Pb[(size_t)m_local * 2048 + n_local] = f2bf(p);
      }
      // sum over the 16 lanes (same row, different cols)
      for (int off = 1; off < 16; off <<= 1) rowpart += __shfl_xor(rowpart, off, 64);
      if (col0 == 0) atomicAdd(&lb[m_local], rowpart);
    }
  }
}

// out[m][d] = (P[m][:] @ vT[d][:]) / l[m].  grid (db, qb, b); causal k-range.
__global__ __launch_bounds__(256) void k_pv(const unsigned short* __restrict__ P,
                                            const unsigned short* __restrict__ vT,
                                            const float* __restrict__ l,
                                            float* __restrict__ out) {
  const int db = blockIdx.x, qb = blockIdx.y, b = blockIdx.z;
  f32x4 acc[4][4];
  const unsigned short* A = P + ((size_t)(b * 2048 + qb * 128)) * 2048;
  const unsigned short* B = vT + ((size_t)(b * 1024 + db * 128)) * 2048;
  mma_mainloop(A, 2048, B, 2048, (qb + 1) * 2, acc);  // keys <= (qb+1)*128
  const int lane = threadIdx.x & 63, wave = threadIdx.x >> 6;
  const int ry = (wave >> 1) * 64, rx = (wave & 1) * 64;
  const int col0 = lane & 15, rq = lane >> 4;
  const float* lb = l + b * 2048 + qb * 128;
  float* ob = out + ((size_t)(b * 2048 + qb * 128)) * 1024 + db * 128;
#pragma unroll
  for (int mi = 0; mi < 4; mi++)
#pragma unroll
    for (int r = 0; r < 4; r++) {
      const int m_local = ry + mi * 16 + rq * 4 + r;
      const float inv = 1.0f / lb[m_local];
#pragma unroll
      for (int nj = 0; nj < 4; nj++) {
        const int n_local = rx + nj * 16 + col0;
        ob[(size_t)m_local * 1024 + n_local] = acc[mi][nj][r] * inv;
      }
    }
}

// ---------------------------------------------------------------------------

extern "C" void kernel_launch(void* const* d_in, const int* in_sizes, int n_in,
                              void* d_out, int out_size, void* d_ws, size_t ws_size,
                              hipStream_t stream) {
  const float* ctx  = (const float*)d_in[0];  // [4,2048,1024]
  const float* W    = (const float*)d_in[1];  // [1024,3072]
  const float* bias = (const float*)d_in[2];  // [3072]
  float* out = (float*)d_out;

  char* ws = (char*)d_ws;
  // workspace layout (bytes): total ~124 MB
  unsigned short* Actx = (unsigned short*)(ws + 0);          // 16,777,216
  unsigned short* Wt   = (unsigned short*)(ws + 16777216);   //  6,291,456
  unsigned short* qkv  = (unsigned short*)(ws + 23068672);   // 50,331,648
  unsigned short* vT   = (unsigned short*)(ws + 73400320);   // 16,777,216
  unsigned short* P    = (unsigned short*)(ws + 90177536);   // 33,554,432
  float*          lsum = (float*)(ws + 123731968);           //     32,768

  hipMemsetAsync(lsum, 0, 4 * 2048 * sizeof(float), stream);
  k_convert<<<8192, 256, 0, stream>>>(ctx, Actx, (8192 * 1024) / 4);
  k_transpose_w<<<dim3(48, 16), 256, 0, stream>>>(W, Wt);
  k_gemm_qkv<<<dim3(24, 64), 256, 0, stream>>>(Actx, Wt, bias, qkv);
  k_transpose_v<<<dim3(16, 32, 4), 256, 0, stream>>>(qkv, vT);
  k_scores<<<dim3(136, 1, 4), 256, 0, stream>>>(qkv, P, lsum, 0.022097086912079608f);
  k_pv<<<dim3(8, 16, 4), 256, 0, stream>>>(P, vT, lsum, out);
}

// Round 3
// 256.956 us; speedup vs baseline: 1.0974x; 1.0206x over previous
//
#include <hip/hip_runtime.h>
#include <cstdint>
#include <cstddef>

// ---------------------------------------------------------------------------
// Attention_84155589198714: qkv = ctx @ W + b; causal softmax(q k^T / sqrt(N)); @ v
// B=4, N=2048, D=1024. All GEMMs in bf16 MFMA (16x16x32), fp32 accumulate.
// Softmax: scores bounded (|s| < ~8) -> no max subtraction; P=exp(s) unnorm,
// row sums via atomics, divide in PV epilogue.
//
// R2: XOR bank swizzle (bank conflicts -> 0, verified).
// R3: (1) operand-swapped MFMA (mfma(b,a)) so each lane's 4 acc regs are 4
//     consecutive COLUMNS -> contiguous ushort4/float4 epilogue stores;
//     (2) V fused into the QKV GEMM with unswapped layout, writing vT[b][d][n]
//     directly (transpose for free, k_transpose_v eliminated);
//     (3) pv qb-flip on half the grid to balance causal work across CUs.
// ---------------------------------------------------------------------------

typedef __attribute__((ext_vector_type(8))) __bf16 bf16x8;
typedef __attribute__((ext_vector_type(4))) float f32x4;

__device__ inline unsigned short f2bf(float f) {
  unsigned u = __float_as_uint(f);
  u = (u + 0x7FFFu + ((u >> 16) & 1u)) >> 16;  // RNE
  return (unsigned short)u;
}

// async global->LDS, 16 B per lane. LDS dest = wave-uniform base + lane*16.
__device__ inline void gld16(const void* g, void* l) {
  __builtin_amdgcn_global_load_lds(
      (const __attribute__((address_space(1))) unsigned int*)g,
      (__attribute__((address_space(3))) unsigned int*)l, 16, 0, 0);
}

// ---------------------------------------------------------------------------
// 128x128-tile bf16 GEMM mainloop, XOR-swizzled LDS, BK=64.
// C[m][n] = sum_k A[m][k] * Bt[n][k].
// SWAP=true: mfma(b,a) -> output tile transposed: lane&15 = m, regs = 4
// consecutive n (contiguous column stores). SWAP=false: lane&15 = n, regs = 4
// consecutive m. LDS passed in so multiple call sites share one allocation.
// ---------------------------------------------------------------------------
template <bool SWAP>
__device__ inline void mma_mainloop(unsigned short* As, unsigned short* Bs,
                                    const unsigned short* Abase, long strideA,
                                    const unsigned short* Bbase, long strideB,
                                    int kIters, f32x4 acc[4][4]) {
  const int tid = threadIdx.x;
  const int lane = tid & 63;
  const int wave = tid >> 6;
  const int ry = (wave >> 1) * 64;
  const int rx = (wave & 1) * 64;
  const int lrow = lane >> 3;                 // 0..7 (row within 8-row chunk)
  const int lcol = ((lane & 7) ^ lrow) * 8;   // swizzled source column-chunk

#pragma unroll
  for (int mi = 0; mi < 4; mi++)
#pragma unroll
    for (int nj = 0; nj < 4; nj++) acc[mi][nj] = (f32x4)(0.f);

  for (int kt = 0; kt < kIters; kt++) {
    const int k0 = kt * 64;
    __syncthreads();  // previous compute done before overwriting LDS
#pragma unroll
    for (int c = 0; c < 4; c++) {
      const int q = wave * 4 + c;     // chunk 0..15, wave-uniform
      const int row = q * 8 + lrow;   // tile row 0..127
      gld16(Abase + (size_t)row * strideA + k0 + lcol, &As[q * 512]);
      gld16(Bbase + (size_t)row * strideB + k0 + lcol, &Bs[q * 512]);
    }
    __syncthreads();  // vmcnt(0) drain before use
#pragma unroll
    for (int kk = 0; kk < 64; kk += 32) {
      const int cbase = (kk >> 3) + (lane >> 4);          // chunk 0..7
      const int csw = ((cbase ^ (lane & 7)) << 3);        // swizzled elem offset
      bf16x8 a[4], b[4];
#pragma unroll
      for (int mi = 0; mi < 4; mi++)
        a[mi] = *(const bf16x8*)&As[(ry + mi * 16 + (lane & 15)) * 64 + csw];
#pragma unroll
      for (int nj = 0; nj < 4; nj++)
        b[nj] = *(const bf16x8*)&Bs[(rx + nj * 16 + (lane & 15)) * 64 + csw];
#pragma unroll
      for (int mi = 0; mi < 4; mi++)
#pragma unroll
        for (int nj = 0; nj < 4; nj++)
          acc[mi][nj] = SWAP
            ? __builtin_amdgcn_mfma_f32_16x16x32_bf16(b[nj], a[mi], acc[mi][nj], 0, 0, 0)
            : __builtin_amdgcn_mfma_f32_16x16x32_bf16(a[mi], b[nj], acc[mi][nj], 0, 0, 0);
    }
  }
}

// --------------------------- prep kernels ----------------------------------

// fp32 -> bf16, 4 elems/thread
__global__ void k_convert(const float* __restrict__ x, unsigned short* __restrict__ y, int n4) {
  int i = blockIdx.x * blockDim.x + threadIdx.x;
  if (i >= n4) return;
  float4 v = ((const float4*)x)[i];
  ushort4 o;
  o.x = f2bf(v.x); o.y = f2bf(v.y); o.z = f2bf(v.z); o.w = f2bf(v.w);
  ((ushort4*)y)[i] = o;
}

// W [1024][3072] fp32 -> Wt [3072][1024] bf16
__global__ void k_transpose_w(const float* __restrict__ W, unsigned short* __restrict__ Wt) {
  __shared__ unsigned short sm[64 * 65];
  const int n0 = blockIdx.x * 64;  // over 3072
  const int k0 = blockIdx.y * 64;  // over 1024
  for (int i = threadIdx.x; i < 4096; i += 256) {
    int r = i >> 6, c = i & 63;  // r = k_local, c = n_local (coalesced in c)
    sm[c * 65 + r] = f2bf(W[(size_t)(k0 + r) * 3072 + n0 + c]);
  }
  __syncthreads();
  for (int i = threadIdx.x; i < 4096; i += 256) {
    int r = i >> 6, c = i & 63;  // r = n_local, c = k_local
    Wt[(size_t)(n0 + r) * 1024 + k0 + c] = sm[r * 65 + c];
  }
}

// --------------------------- GEMM kernels ----------------------------------

// Fused QKV GEMM. blockIdx.x < 16: q,k features -> qk[8192][2048] (SWAP path,
// contiguous ushort4 row stores). blockIdx.x >= 16: v features -> vT[b][d][n]
// (unswapped path: regs = consecutive m = consecutive seq -> contiguous
// ushort4 stores into the TRANSPOSED layout for free).
__global__ __launch_bounds__(256) void k_gemm_qkv(const unsigned short* __restrict__ A,
                                                  const unsigned short* __restrict__ Wt,
                                                  const float* __restrict__ bias,
                                                  unsigned short* __restrict__ qk,
                                                  unsigned short* __restrict__ vT) {
  __shared__ unsigned short As[128 * 64];
  __shared__ unsigned short Bs[128 * 64];
  f32x4 acc[4][4];
  const int tM0 = blockIdx.y * 128;
  const int lane = threadIdx.x & 63, wave = threadIdx.x >> 6;
  const int ry = (wave >> 1) * 64, rx = (wave & 1) * 64;
  const int l16 = lane & 15, rq = lane >> 4;

  if (blockIdx.x < 16) {
    const int tN0 = blockIdx.x * 128;  // feature 0..2047 (q,k)
    mma_mainloop<true>(As, Bs, A + (size_t)tM0 * 1024, 1024,
                       Wt + (size_t)tN0 * 1024, 1024, 16, acc);
#pragma unroll
    for (int mi = 0; mi < 4; mi++) {
      const int m = tM0 + ry + mi * 16 + l16;
#pragma unroll
      for (int nj = 0; nj < 4; nj++) {
        const int n = tN0 + rx + nj * 16 + rq * 4;
        const float4 bv = *(const float4*)&bias[n];
        ushort4 o;
        o.x = f2bf(acc[mi][nj][0] + bv.x);
        o.y = f2bf(acc[mi][nj][1] + bv.y);
        o.z = f2bf(acc[mi][nj][2] + bv.z);
        o.w = f2bf(acc[mi][nj][3] + bv.w);
        *(ushort4*)&qk[(size_t)m * 2048 + n] = o;
      }
    }
  } else {
    const int tN0 = (blockIdx.x - 16) * 128;  // v feature d0 0..1023
    mma_mainloop<false>(As, Bs, A + (size_t)tM0 * 1024, 1024,
                        Wt + (size_t)(2048 + tN0) * 1024, 1024, 16, acc);
#pragma unroll
    for (int nj = 0; nj < 4; nj++) {
      const int d = tN0 + rx + nj * 16 + l16;
      const float bv = bias[2048 + d];
#pragma unroll
      for (int mi = 0; mi < 4; mi++) {
        const int m = tM0 + ry + mi * 16 + rq * 4;  // global seq index (4 consecutive)
        const int b = m >> 11, ns = m & 2047;
        ushort4 o;
        o.x = f2bf(acc[mi][nj][0] + bv);
        o.y = f2bf(acc[mi][nj][1] + bv);
        o.z = f2bf(acc[mi][nj][2] + bv);
        o.w = f2bf(acc[mi][nj][3] + bv);
        *(ushort4*)&vT[((size_t)(b * 1024 + d)) * 2048 + ns] = o;
      }
    }
  }
}

// P_unnorm tile + row-sum atomics. 1-D triangular grid over (qb,kb), z = batch.
__global__ __launch_bounds__(256) void k_scores(const unsigned short* __restrict__ qk,
                                                unsigned short* __restrict__ P,
                                                float* __restrict__ l, float scale) {
  __shared__ unsigned short As[128 * 64];
  __shared__ unsigned short Bs[128 * 64];
  const int t = blockIdx.x, b = blockIdx.z;
  int qb = (int)((sqrtf(8.0f * (float)t + 1.0f) - 1.0f) * 0.5f);
  while (qb * (qb + 1) / 2 > t) qb--;            // guard fp rounding
  while ((qb + 1) * (qb + 2) / 2 <= t) qb++;
  const int kb = t - qb * (qb + 1) / 2;
  f32x4 acc[4][4];
  const unsigned short* Aq = qk + ((size_t)(b * 2048 + qb * 128)) * 2048;         // q rows
  const unsigned short* Bk = qk + ((size_t)(b * 2048 + kb * 128)) * 2048 + 1024;  // k rows
  mma_mainloop<true>(As, Bs, Aq, 2048, Bk, 2048, 16, acc);
  const int lane = threadIdx.x & 63, wave = threadIdx.x >> 6;
  const int ry = (wave >> 1) * 64, rx = (wave & 1) * 64;
  const int l16 = lane & 15, rq = lane >> 4;
  unsigned short* Pb = P + ((size_t)(b * 2048 + qb * 128)) * 2048 + (size_t)kb * 128;
  float* lb = l + b * 2048 + qb * 128;
#pragma unroll
  for (int mi = 0; mi < 4; mi++) {
    const int m_local = ry + mi * 16 + l16;
    const int qi = qb * 128 + m_local;
    float rowpart = 0.f;
#pragma unroll
    for (int nj = 0; nj < 4; nj++) {
      const int n_base = rx + nj * 16 + rq * 4;
      ushort4 o;
      float p;
#pragma unroll
      for (int r = 0; r < 4; r++) {
        const int kj = kb * 128 + n_base + r;
        p = (kj <= qi) ? __expf(acc[mi][nj][r] * scale) : 0.f;  // bounded, no max
        rowpart += p;
        ((unsigned short*)&o)[r] = f2bf(p);
      }
      *(ushort4*)&Pb[(size_t)m_local * 2048 + n_base] = o;
    }
    // lanes {l16, l16+16, l16+32, l16+48} hold partial sums of the same row
    rowpart += __shfl_xor(rowpart, 16, 64);
    rowpart += __shfl_xor(rowpart, 32, 64);
    if (rq == 0) atomicAdd(&lb[m_local], rowpart);
  }
}

// out[m][d] = (P[m][:] @ vT[d][:]) / l[m].  grid (db, qb, b); causal k-range.
// qb flipped for z>=2 so each CU pairs a deep tile with a shallow one.
__global__ __launch_bounds__(256) void k_pv(const unsigned short* __restrict__ P,
                                            const unsigned short* __restrict__ vT,
                                            const float* __restrict__ l,
                                            float* __restrict__ out) {
  __shared__ unsigned short As[128 * 64];
  __shared__ unsigned short Bs[128 * 64];
  const int db = blockIdx.x, b = blockIdx.z;
  int qb = blockIdx.y;
  if (b & 2) qb = 15 - qb;  // load balance across CUs
  f32x4 acc[4][4];
  const unsigned short* Ap = P + ((size_t)(b * 2048 + qb * 128)) * 2048;
  const unsigned short* Bv = vT + ((size_t)(b * 1024 + db * 128)) * 2048;
  mma_mainloop<true>(As, Bs, Ap, 2048, Bv, 2048, (qb + 1) * 2, acc);  // keys <= (qb+1)*128
  const int lane = threadIdx.x & 63, wave = threadIdx.x >> 6;
  const int ry = (wave >> 1) * 64, rx = (wave & 1) * 64;
  const int l16 = lane & 15, rq = lane >> 4;
  const float* lb = l + b * 2048 + qb * 128;
  float* ob = out + ((size_t)(b * 2048 + qb * 128)) * 1024 + db * 128;
#pragma unroll
  for (int mi = 0; mi < 4; mi++) {
    const int m_local = ry + mi * 16 + l16;
    const float inv = 1.0f / lb[m_local];
#pragma unroll
    for (int nj = 0; nj < 4; nj++) {
      const int n_base = rx + nj * 16 + rq * 4;
      float4 o;
      o.x = acc[mi][nj][0] * inv;
      o.y = acc[mi][nj][1] * inv;
      o.z = acc[mi][nj][2] * inv;
      o.w = acc[mi][nj][3] * inv;
      *(float4*)&ob[(size_t)m_local * 1024 + n_base] = o;
    }
  }
}

// ---------------------------------------------------------------------------

extern "C" void kernel_launch(void* const* d_in, const int* in_sizes, int n_in,
                              void* d_out, int out_size, void* d_ws, size_t ws_size,
                              hipStream_t stream) {
  const float* ctx  = (const float*)d_in[0];  // [4,2048,1024]
  const float* W    = (const float*)d_in[1];  // [1024,3072]
  const float* bias = (const float*)d_in[2];  // [3072]
  float* out = (float*)d_out;

  char* ws = (char*)d_ws;
  // workspace layout (bytes): total ~107 MB
  unsigned short* Actx = (unsigned short*)(ws + 0);          // 16,777,216
  unsigned short* Wt   = (unsigned short*)(ws + 16777216);   //  6,291,456
  unsigned short* qk   = (unsigned short*)(ws + 23068672);   // 33,554,432
  unsigned short* vT   = (unsigned short*)(ws + 56623104);   // 16,777,216
  unsigned short* P    = (unsigned short*)(ws + 73400320);   // 33,554,432
  float*          lsum = (float*)(ws + 106954752);           //     32,768

  hipMemsetAsync(lsum, 0, 4 * 2048 * sizeof(float), stream);
  k_convert<<<8192, 256, 0, stream>>>(ctx, Actx, (8192 * 1024) / 4);
  k_transpose_w<<<dim3(48, 16), 256, 0, stream>>>(W, Wt);
  k_gemm_qkv<<<dim3(24, 64), 256, 0, stream>>>(Actx, Wt, bias, qk, vT);
  k_scores<<<dim3(136, 1, 4), 256, 0, stream>>>(qk, P, lsum, 0.022097086912079608f);
  k_pv<<<dim3(8, 16, 4), 256, 0, stream>>>(P, vT, lsum, out);
}